// Round 22
// baseline (175.566 us; speedup 1.0000x reference)
//
#include <hip/hip_runtime.h>
#include <math.h>

#define B_ 16
#define T_ 12
#define N_ 1024
#define D_ 64
#define HS_ 16
#define HT_ 64
#define TT_ 192
#define BT_ 192

typedef _Float16 f16x2 __attribute__((ext_vector_type(2)));
typedef _Float16 f16x8v __attribute__((ext_vector_type(8)));
typedef float f32x4v __attribute__((ext_vector_type(4)));
typedef unsigned int u32x4v __attribute__((ext_vector_type(4)));

__device__ __forceinline__ unsigned int pkrtz(float a, float b){
    auto r = __builtin_amdgcn_cvt_pkrtz(a, b);
    return __builtin_bit_cast(unsigned int, r);
}
__device__ __forceinline__ float fdot2u(unsigned int a, unsigned int b, float c){
    return __builtin_amdgcn_fdot2(__builtin_bit_cast(f16x2, a),
                                  __builtin_bit_cast(f16x2, b), c, false);
}
__device__ __forceinline__ float loF(unsigned int a){ f16x2 h = __builtin_bit_cast(f16x2, a); return (float)h.x; }
__device__ __forceinline__ float hiF(unsigned int a){ f16x2 h = __builtin_bit_cast(f16x2, a); return (float)h.y; }
__device__ __forceinline__ f32x4v mfma16(u32x4v a, u32x4v b, f32x4v c){
    return __builtin_amdgcn_mfma_f32_16x16x32_f16(
        __builtin_bit_cast(f16x8v, a), __builtin_bit_cast(f16x8v, b), c, 0, 0, 0);
}

__device__ __forceinline__ float lrelu_(float v){ return v > 0.f ? v : 0.01f*v; }
__device__ __forceinline__ float squash_sc(float sn){ return (sn/(1.f+sn))/(sqrtf(sn)+1e-8f); }

__device__ __forceinline__ float wredsum64(float v){
    #pragma unroll
    for (int mk = 1; mk < 64; mk <<= 1) v += __shfl_xor(v, mk, 64);
    return v;
}

// PLT XOR-swizzle (round-19 verified): word (d,np) at d*68 + (np ^ ((d>>3)<<2)).

// ---------------------------------------------------------------------------
// k_dadj: dadj[bt,h,n] = sum_e teb[bt,e]*adj[e,h,n]   grid (192,16) x 256
// ---------------------------------------------------------------------------
__global__ __launch_bounds__(256) void k_dadj(const float* __restrict__ teb,
        const float* __restrict__ adj, float* __restrict__ dadj){
    int bt = blockIdx.x, h = blockIdx.y, n4 = threadIdx.x;
    float tl[16];
    #pragma unroll
    for (int e = 0; e < 16; ++e) tl[e] = teb[bt*16 + e];
    float4 acc = {0.f,0.f,0.f,0.f};
    #pragma unroll
    for (int e = 0; e < 16; ++e){
        float4 a = ((const float4*)(adj + ((size_t)(e*16 + h) << 10)))[n4];
        acc.x += tl[e]*a.x; acc.y += tl[e]*a.y;
        acc.z += tl[e]*a.z; acc.w += tl[e]*a.w;
    }
    ((float4*)(dadj + ((size_t)bt*16 + h)*1024))[n4] = acc;
}

// ---------------------------------------------------------------------------
// k_PA0: fused k_P (MFMA y=x@W^T+b) + pass-0 sweep. dadj precomputed.
// Round-22: x staged via float4 (16B/lane coalescing sweet spot).
// LDS 40448 B -> 4 blocks/CU.  grid (192,8) x 256
// ---------------------------------------------------------------------------
__global__ __launch_bounds__(256, 1) void k_PA0(const float* __restrict__ x,
        const float* __restrict__ Wp, const float* __restrict__ bp,
        unsigned int* __restrict__ Ppk, float* __restrict__ scb,
        const float* __restrict__ dadjb,
        float* __restrict__ tpOut, float* __restrict__ spOut){
    __shared__ unsigned int xst[128*36];       // x-stage, then packed y
    __shared__ unsigned int PLT[64*68];
    __shared__ unsigned int cpk[16*68];
    __shared__ unsigned int scpk[64];
    int t = threadIdx.x, w = t >> 6, l = t & 63;
    int lr = l & 15, lk = l >> 4;
    int bt = blockIdx.x, ch = blockIdx.y;
    int n0 = ch*128;
    size_t rbase = (size_t)bt*1024 + n0;
    const float* xb = x + rbase*64;

    // ---- phase 1: stage x (f16 pairs) via float4 loads
    #pragma unroll
    for (int j = 0; j < 8; ++j){
        int idx = j*256 + t;               // 0..2047 float4s
        int row = idx >> 4, q4 = idx & 15;
        float4 xv = *(const float4*)(xb + row*64 + 4*q4);
        xst[row*36 + 2*q4]     = pkrtz(xv.x, xv.y);
        xst[row*36 + 2*q4 + 1] = pkrtz(xv.z, xv.w);
    }
    f16x8v bf[4][2];
    float bpv[4];
    #pragma unroll
    for (int nt = 0; nt < 4; ++nt){
        #pragma unroll
        for (int ks = 0; ks < 2; ++ks){
            const float* wr = Wp + (nt*16 + lr)*64 + ks*32 + lk*8;
            u32x4v bw;
            #pragma unroll
            for (int j = 0; j < 4; ++j){
                float2 w2 = *(const float2*)(wr + 2*j);
                bw[j] = pkrtz(w2.x, w2.y);
            }
            bf[nt][ks] = __builtin_bit_cast(f16x8v, bw);
        }
        bpv[nt] = bp[nt*16 + lr];
    }
    __syncthreads();

    // ---- phase 2: y = x@W^T + b via MFMA; pack back into xst rows
    #pragma unroll
    for (int mi = 0; mi < 2; ++mi){
        int mt = 2*w + mi;
        f32x4v acc0 = {0.f,0.f,0.f,0.f}, acc1 = {0.f,0.f,0.f,0.f};
        f32x4v acc2 = {0.f,0.f,0.f,0.f}, acc3 = {0.f,0.f,0.f,0.f};
        #pragma unroll
        for (int ks = 0; ks < 2; ++ks){
            u32x4v au = *(u32x4v*)&xst[(mt*16 + lr)*36 + ks*16 + lk*4];
            f16x8v af = __builtin_bit_cast(f16x8v, au);
            acc0 = __builtin_amdgcn_mfma_f32_16x16x32_f16(af, bf[0][ks], acc0, 0, 0, 0);
            acc1 = __builtin_amdgcn_mfma_f32_16x16x32_f16(af, bf[1][ks], acc1, 0, 0, 0);
            acc2 = __builtin_amdgcn_mfma_f32_16x16x32_f16(af, bf[2][ks], acc2, 0, 0, 0);
            acc3 = __builtin_amdgcn_mfma_f32_16x16x32_f16(af, bf[3][ks], acc3, 0, 0, 0);
        }
        #pragma unroll
        for (int i = 0; i < 4; ++i){
            int row = mt*16 + lk*4 + i;
            float y0 = acc0[i] + bpv[0];
            float y1 = acc1[i] + bpv[1];
            float y2 = acc2[i] + bpv[2];
            float y3 = acc3[i] + bpv[3];
            float p0 = __shfl_xor(y0, 1, 64);
            float p1 = __shfl_xor(y1, 1, 64);
            float p2 = __shfl_xor(y2, 1, 64);
            float p3 = __shfl_xor(y3, 1, 64);
            if (!(l & 1)){
                int cb = lr >> 1;
                xst[row*36 +      cb] = pkrtz(y0, p0);
                xst[row*36 +  8 + cb] = pkrtz(y1, p1);
                xst[row*36 + 16 + cb] = pkrtz(y2, p2);
                xst[row*36 + 24 + cb] = pkrtz(y3, p3);
            }
        }
    }
    __syncthreads();

    // ---- phase 3: write Ppk + build PLT (swizzled transpose write)
    unsigned int* pb = Ppk + rbase*32;
    #pragma unroll
    for (int k = 0; k < 4; ++k){
        int idx4 = k*256 + t;
        int nn = idx4 >> 3, jq = idx4 & 7;
        uint4 u;
        u.x = xst[nn*36 + 4*jq];     u.y = xst[nn*36 + 4*jq + 1];
        u.z = xst[nn*36 + 4*jq + 2]; u.w = xst[nn*36 + 4*jq + 3];
        ((uint4*)pb)[idx4] = u;
        unsigned int px = __shfl_xor(u.x, 8, 64);
        unsigned int py = __shfl_xor(u.y, 8, 64);
        unsigned int pz = __shfl_xor(u.z, 8, 64);
        unsigned int pw = __shfl_xor(u.w, 8, 64);
        if (!(nn & 1)){
            int np = nn >> 1, d0 = jq*8;
            int cs = np ^ (jq << 2);
            PLT[(d0+0)*68 + cs] = (u.x & 0xFFFFu) | (px << 16);
            PLT[(d0+1)*68 + cs] = (u.x >> 16)     | (px & 0xFFFF0000u);
            PLT[(d0+2)*68 + cs] = (u.y & 0xFFFFu) | (py << 16);
            PLT[(d0+3)*68 + cs] = (u.y >> 16)     | (py & 0xFFFF0000u);
            PLT[(d0+4)*68 + cs] = (u.z & 0xFFFFu) | (pz << 16);
            PLT[(d0+5)*68 + cs] = (u.z >> 16)     | (pz & 0xFFFF0000u);
            PLT[(d0+6)*68 + cs] = (u.w & 0xFFFFu) | (pw << 16);
            PLT[(d0+7)*68 + cs] = (u.w >> 16)     | (pw & 0xFFFF0000u);
        }
    }

    // ---- phase 5 (t<128): |y|^2 + sc; logits from precomputed dadj; softmax
    if (t < 128){
        int nn = t;
        float s2 = 0.f;
        #pragma unroll
        for (int j = 0; j < 8; ++j){
            uint4 pq = *(uint4*)&xst[nn*36 + 4*j];
            s2 += loF(pq.x)*loF(pq.x) + hiF(pq.x)*hiF(pq.x);
            s2 += loF(pq.y)*loF(pq.y) + hiF(pq.y)*hiF(pq.y);
            s2 += loF(pq.z)*loF(pq.z) + hiF(pq.z)*hiF(pq.z);
            s2 += loF(pq.w)*loF(pq.w) + hiF(pq.w)*hiF(pq.w);
        }
        float scn = squash_sc(s2);
        scb[(size_t)bt*1024 + n0 + nn] = scn;
        float so = __shfl_xor(scn, 1, 64);
        if (!(nn & 1)) scpk[nn >> 1] = pkrtz(scn, so);
        float lg[16];
        #pragma unroll
        for (int h = 0; h < 16; ++h)
            lg[h] = dadjb[((size_t)bt*16 + h)*1024 + n0 + nn];
        float M = -1e30f;
        #pragma unroll
        for (int h = 0; h < 16; ++h) M = fmaxf(M, lg[h]);
        float S = 0.f;
        #pragma unroll
        for (int h = 0; h < 16; ++h){ lg[h] = __expf(lg[h] - M); S += lg[h]; }
        float inv = 1.f/S;
        #pragma unroll
        for (int h = 0; h < 16; ++h){
            float cs = lg[h]*inv*scn;
            float co = __shfl_xor(cs, 1, 64);
            if (!(nn & 1)) cpk[h*68 + (nn >> 1)] = pkrtz(cs, co);
        }
    }
    __syncthreads();

    // ---- phase 6: cP MFMA (D[h][d] = cpk x PLT) + sumP (swizzled reads)
    {
        int swd = ((w*16 + lr) >> 3) << 2;
        f32x4v acc = {0.f,0.f,0.f,0.f};
        #pragma unroll
        for (int ks = 0; ks < 4; ++ks){
            u32x4v au = *(u32x4v*)&cpk[lr*68 + ks*16 + lk*4];
            u32x4v bu = *(u32x4v*)&PLT[(w*16 + lr)*68 + ((ks*16 + lk*4) ^ swd)];
            acc = mfma16(au, bu, acc);
        }
        #pragma unroll
        for (int i = 0; i < 4; ++i){
            int h = lk*4 + i;
            tpOut[(((size_t)bt*8 + ch)*16 + h)*64 + w*16 + lr] = acc[i];
        }
    }
    if (w == 0){
        int sl = (l >> 3) << 2;
        float sp2 = 0.f;
        #pragma unroll
        for (int np4 = 0; np4 < 16; ++np4){
            uint4 pq = *(uint4*)&PLT[l*68 + ((4*np4) ^ sl)];
            uint4 sq = *(uint4*)&scpk[4*np4];
            sp2 = fdot2u(pq.x, sq.x, sp2);
            sp2 = fdot2u(pq.y, sq.y, sp2);
            sp2 = fdot2u(pq.z, sq.z, sp2);
            sp2 = fdot2u(pq.w, sq.w, sp2);
        }
        spOut[((size_t)bt*8 + ch)*64 + l] = sp2;
    }
}

// ---------------------------------------------------------------------------
// kA (modes 1-3): no PL buffer; logit A-fragments direct from Ppk (L2-hot).
// grid (192,8) x 256
// ---------------------------------------------------------------------------
template<int MODE>
__global__ __launch_bounds__(256, 2) void kA(const unsigned int* __restrict__ Ppk,
        float* __restrict__ scb,
        float* __restrict__ dadjb,
        const float* __restrict__ tpIn, const float* __restrict__ spart,
        float* __restrict__ v1buf, const float* __restrict__ vsumIn,
        float* __restrict__ vsumOut,
        float* __restrict__ tpOut, float* __restrict__ cout){
    __shared__ unsigned int PLT[64*68];
    __shared__ unsigned int vLp[16*36];
    __shared__ float bL[16*130];
    __shared__ unsigned int cpk[16*68];
    __shared__ float scL[128];
    int bt = blockIdx.x, ch = blockIdx.y;
    int t = threadIdx.x, w = t >> 6, l = t & 63;
    int lr = l & 15, lk = l >> 4;
    int n0 = ch*128;
    size_t rbase = (size_t)bt*1024 + n0;

    const uint4* Pg = (const uint4*)(Ppk + rbase*32);
    #pragma unroll
    for (int k = 0; k < 4; ++k){
        int idx4 = t + 256*k;
        uint4 u = Pg[idx4];
        int nn = idx4 >> 3, jq = idx4 & 7;
        unsigned int px = __shfl_xor(u.x, 8, 64);
        unsigned int py = __shfl_xor(u.y, 8, 64);
        unsigned int pz = __shfl_xor(u.z, 8, 64);
        unsigned int pw = __shfl_xor(u.w, 8, 64);
        if (!(nn & 1)){
            int np = nn >> 1, d0 = jq*8;
            int cs = np ^ (jq << 2);
            PLT[(d0+0)*68 + cs] = (u.x & 0xFFFFu) | (px << 16);
            PLT[(d0+1)*68 + cs] = (u.x >> 16)     | (px & 0xFFFF0000u);
            PLT[(d0+2)*68 + cs] = (u.y & 0xFFFFu) | (py << 16);
            PLT[(d0+3)*68 + cs] = (u.y >> 16)     | (py & 0xFFFF0000u);
            PLT[(d0+4)*68 + cs] = (u.z & 0xFFFFu) | (pz << 16);
            PLT[(d0+5)*68 + cs] = (u.z >> 16)     | (pz & 0xFFFF0000u);
            PLT[(d0+6)*68 + cs] = (u.w & 0xFFFFu) | (pw << 16);
            PLT[(d0+7)*68 + cs] = (u.w >> 16)     | (pw & 0xFFFF0000u);
        }
    }
    if (t < 128) scL[t] = scb[(size_t)bt*1024 + n0 + t];
    {
        float sp = 0.f;
        if (MODE == 1){
            #pragma unroll
            for (int c = 0; c < 8; ++c) sp += spart[((size_t)bt*8 + c)*64 + l];
            sp *= (1.f/16.f);
        }
        #pragma unroll
        for (int i = 0; i < 4; ++i){
            int h = 4*w + i;
            float s = 0.f;
            #pragma unroll
            for (int c = 0; c < 8; ++c)
                s += tpIn[(((size_t)bt*8 + c)*16 + h)*64 + l];
            size_t oi = ((size_t)bt*16 + h)*64 + l;
            float vs;
            if (MODE == 1){
                float sn = wredsum64(s*s);
                float v1 = s*squash_sc(sn);
                v1buf[oi] = v1;
                float q = v1*sp;
                float sn2 = wredsum64(q*q);
                vs = q*squash_sc(sn2);
            } else {
                float q = v1buf[oi]*s;
                float sn = wredsum64(q*q);
                vs = vsumIn[oi] + q*squash_sc(sn);
            }
            if (MODE != 3) vsumOut[oi] = vs;
            float vo = __shfl_xor(vs, 1, 64);
            if (!(l & 1)) vLp[h*36 + (l >> 1)] = pkrtz(vs, vo);
        }
    }
    __syncthreads();

    // logit MFMA: A-fragments direct from global Ppk (L2-hot); D[n][h]
    #pragma unroll
    for (int mi = 0; mi < 2; ++mi){
        int mt = 2*w + mi;
        f32x4v acc = {0.f,0.f,0.f,0.f};
        #pragma unroll
        for (int ks = 0; ks < 2; ++ks){
            u32x4v au = *(const u32x4v*)(Ppk + (rbase + mt*16 + lr)*32 + ks*16 + lk*4);
            u32x4v bu = *(u32x4v*)&vLp[lr*36 + ks*16 + lk*4];
            acc = mfma16(au, bu, acc);
        }
        #pragma unroll
        for (int i = 0; i < 4; ++i){
            int nn = mt*16 + lk*4 + i;
            float lg = acc[i] * scL[nn];
            if (MODE == 3)
                lg += dadjb[((size_t)bt*16 + lr)*1024 + n0 + nn];
            bL[lr*130 + nn] = lg;
        }
    }
    __syncthreads();

    // softmax over h per n; pack cpk = c*sc
    if (t < 128){
        int nn = t;
        float scn = scL[nn];
        float M = -1e30f;
        #pragma unroll
        for (int h = 0; h < 16; ++h) M = fmaxf(M, bL[h*130 + nn]);
        float S = 0.f; float ev[16];
        #pragma unroll
        for (int h = 0; h < 16; ++h){ ev[h] = __expf(bL[h*130 + nn] - M); S += ev[h]; }
        float inv = 1.f/S;
        #pragma unroll
        for (int h = 0; h < 16; ++h){
            float cv = ev[h]*inv;
            if (MODE == 3) cout[((size_t)bt*16 + h)*1024 + n0 + nn] = cv;
            float cs = cv*scn;
            float co = __shfl_xor(cs, 1, 64);
            if (!(nn & 1)) cpk[h*68 + (nn >> 1)] = pkrtz(cs, co);
        }
    }
    __syncthreads();

    // cP MFMA: wave w -> d-tile w; D[h][d] (swizzled B-read)
    {
        int swd = ((w*16 + lr) >> 3) << 2;
        f32x4v acc = {0.f,0.f,0.f,0.f};
        #pragma unroll
        for (int ks = 0; ks < 4; ++ks){
            u32x4v au = *(u32x4v*)&cpk[lr*68 + ks*16 + lk*4];
            u32x4v bu = *(u32x4v*)&PLT[(w*16 + lr)*68 + ((ks*16 + lk*4) ^ swd)];
            acc = mfma16(au, bu, acc);
        }
        #pragma unroll
        for (int i = 0; i < 4; ++i){
            int h = lk*4 + i;
            tpOut[(((size_t)bt*8 + ch)*16 + h)*64 + w*16 + lr] = acc[i];
        }
    }
}

// k_s: s = reduce tpart (raw)   grid 192 x 256
__global__ __launch_bounds__(256) void k_s(const float* __restrict__ tpart,
        float* __restrict__ sout){
    int bt = blockIdx.x;
    int w = threadIdx.x >> 6, l = threadIdx.x & 63;
    #pragma unroll
    for (int i = 0; i < 4; ++i){
        int h = 4*w + i;
        float s = 0.f;
        #pragma unroll
        for (int c = 0; c < 8; ++c)
            s += tpart[(((size_t)bt*8 + c)*16 + h)*64 + l];
        sout[((size_t)bt*16 + h)*64 + l] = s;
    }
}

// k_wsp: precompute w_sp/b_sp per node.  grid (8,32) x 256
__global__ __launch_bounds__(256) void k_wsp(const float* __restrict__ ne,
        const float* __restrict__ wspa, const float* __restrict__ bspa,
        unsigned int* __restrict__ wpkg, float* __restrict__ bspg){
    __shared__ float wspaL[16*512];
    __shared__ float neL[32*16];
    int ioc = blockIdx.x, nc = blockIdx.y;
    int t = threadIdx.x, w = t >> 6, o = t & 63;
    #pragma unroll
    for (int k = 0; k < 8; ++k){
        int idx4 = t + 256*k;
        int e = idx4 >> 7, j4 = idx4 & 127;
        *(float4*)&wspaL[e*512 + 4*j4] =
            *(const float4*)(wspa + (size_t)e*4096 + ioc*512 + 4*j4);
    }
    #pragma unroll
    for (int k = 0; k < 2; ++k)
        neL[k*256 + t] = ne[(size_t)nc*512 + k*256 + t];
    __syncthreads();
    int c0 = (2*w)*64 + o, c1 = (2*w+1)*64 + o;
    #pragma unroll 2
    for (int n = 0; n < 32; ++n){
        float a0 = 0.f, a1 = 0.f;
        #pragma unroll
        for (int e = 0; e < 16; ++e){
            float nv = neL[n*16 + e];
            a0 += nv*wspaL[e*512 + c0];
            a1 += nv*wspaL[e*512 + c1];
        }
        wpkg[((size_t)(nc*32 + n))*2048 + (ioc*4 + w)*64 + o] = pkrtz(a0, a1);
    }
    if (ioc == 0){
        #pragma unroll
        for (int k = 0; k < 8; ++k){
            int idx = k*256 + t;
            int n = idx >> 6, o2 = idx & 63;
            float a = 0.f;
            #pragma unroll
            for (int e = 0; e < 16; ++e)
                a += neL[n*16 + e]*bspa[e*64 + o2];
            bspg[(size_t)(nc*32 + n)*64 + o2] = a;
        }
    }
}

// k_dyntem: fused dyn + tem.  grid (16,64) x 256
__global__ __launch_bounds__(256) void k_dyntem(const float* __restrict__ timeb,
        const float* __restrict__ tadj, const float* __restrict__ sbuf,
        float* __restrict__ dyn, float* __restrict__ tem){
    __shared__ float dynL[192];
    __shared__ float part[4][64];
    int b = blockIdx.x, h = blockIdx.y, t = threadIdx.x;
    if (t < 192){
        float a = 0.f;
        #pragma unroll
        for (int e = 0; e < 16; ++e)
            a += timeb[b*16 + e]*tadj[((size_t)e*HT_ + h)*TT_ + t];
        dynL[t] = a;
        dyn[((size_t)b*HT_ + h)*TT_ + t] = a;
    }
    __syncthreads();
    int p = t >> 6, d = t & 63;
    const float* sb = sbuf + (size_t)b*TT_*64;
    float a = 0.f;
    #pragma unroll 4
    for (int k = 48*p; k < 48*p + 48; ++k)
        a += dynL[k]*(sb[(size_t)k*64 + d] + (float)((k >> 4) + 1)*(1.f/12.f));
    part[p][d] = a;
    __syncthreads();
    if (t < 64)
        tem[((size_t)b*HT_ + h)*64 + t] =
            lrelu_(part[0][t] + part[1][t] + part[2][t] + part[3][t]);
}

// ret=lrelu(sum_h dyn*tem)+s; v2=squash(ret)   grid (16,48) x 256
__global__ __launch_bounds__(256) void k_retv2(const float* __restrict__ dyn,
        const float* __restrict__ temb, const float* __restrict__ sbuf,
        float* __restrict__ v2){
    int b = blockIdx.x, kg = blockIdx.y;
    int w = threadIdx.x >> 6, l = threadIdx.x & 63;
    int k = kg*4 + w;
    const float* tb = temb + (size_t)b*HT_*64;
    float a0 = 0.f, a1 = 0.f;
    #pragma unroll 4
    for (int h = 0; h < HT_; h += 2){
        a0 += dyn[((size_t)b*HT_ + h  )*TT_ + k] * tb[(size_t)h*64 + l];
        a1 += dyn[((size_t)b*HT_ + h+1)*TT_ + k] * tb[(size_t)(h+1)*64 + l];
    }
    float a = lrelu_(a0 + a1);
    float r = a + sbuf[((size_t)b*TT_ + k)*64 + l];
    float sn = wredsum64(r*r);
    v2[((size_t)b*TT_ + k)*64 + l] = r*squash_sc(sn);
}

// recon f16 pairs, layout [n][bt][32]   grid (192,8) x 256
__global__ __launch_bounds__(256) void k_rec(const float* __restrict__ cbuf,
        const float* __restrict__ v2, unsigned int* __restrict__ recpk){
    __shared__ float vL[16*68];
    __shared__ float cL[16*132];
    int bt = blockIdx.x, nc = blockIdx.y;
    int t = threadIdx.x, l = t & 63, g = t >> 6;
    #pragma unroll
    for (int i = 0; i < 4; ++i){
        int idx = i*256 + t;
        vL[(idx>>6)*68 + (idx&63)] = v2[(size_t)bt*1024 + idx];
    }
    #pragma unroll
    for (int i = 0; i < 8; ++i){
        int idx = i*256 + t;
        cL[(idx>>7)*132 + (idx&127)] =
            cbuf[((size_t)bt*16 + (idx>>7))*1024 + nc*128 + (idx&127)];
    }
    __syncthreads();
    float vreg[16];
    #pragma unroll
    for (int h = 0; h < 16; ++h) vreg[h] = vL[h*68 + l];
    #pragma unroll 4
    for (int i = 0; i < 32; ++i){
        int nl = g + 4*i;
        float a = 0.f;
        #pragma unroll
        for (int h = 0; h < 16; ++h) a += cL[h*132 + nl]*vreg[h];
        float ap = __shfl_xor(a, 1, 64);
        if (!(l & 1))
            recpk[((size_t)(nc*128 + nl)*192 + bt)*32 + (l>>1)] = pkrtz(a, ap);
    }
}

// out = lrelu(rec @ wsp[n] + bsp[n] + x)   grid (1024,2) x 256
__global__ __launch_bounds__(256) void k_final(const float* __restrict__ x,
        const unsigned int* __restrict__ wpkg, const float* __restrict__ bspg,
        const unsigned int* __restrict__ recpk, float* __restrict__ out){
    __shared__ __align__(16) unsigned int recL[96*32];
    int n = blockIdx.x, half = blockIdx.y;
    int t = threadIdx.x, l = t & 63, g = t >> 6;
    unsigned int wr[32];
    const unsigned int* wn = wpkg + (size_t)n*2048;
    #pragma unroll
    for (int ip = 0; ip < 32; ++ip) wr[ip] = wn[ip*64 + l];
    float bsp = bspg[(size_t)n*64 + l];
    {
        const uint4* src = (const uint4*)(recpk + ((size_t)n*192 + half*96)*32);
        #pragma unroll
        for (int k = 0; k < 3; ++k)
            ((uint4*)recL)[t + 256*k] = src[t + 256*k];
    }
    __syncthreads();
    #pragma unroll 2
    for (int i = 0; i < 24; ++i){
        int r = i*4 + g;
        int bt = half*96 + r;
        const uint4* rp = (const uint4*)&recL[r*32];
        float o0 = bsp, o1 = 0.f;
        #pragma unroll
        for (int jj = 0; jj < 8; ++jj){
            uint4 rq = rp[jj];
            o0 = fdot2u(rq.x, wr[4*jj+0], o0);
            o1 = fdot2u(rq.y, wr[4*jj+1], o1);
            o0 = fdot2u(rq.z, wr[4*jj+2], o0);
            o1 = fdot2u(rq.w, wr[4*jj+3], o1);
        }
        size_t oidx = ((size_t)bt*1024 + n)*64 + l;
        out[oidx] = lrelu_(o0 + o1 + x[oidx]);
    }
}

extern "C" void kernel_launch(void* const* d_in, const int* in_sizes, int n_in,
                              void* d_out, int out_size, void* d_ws, size_t ws_size,
                              hipStream_t stream) {
    const float* x     = (const float*)d_in[0];
    const float* ne    = (const float*)d_in[1];
    const float* timeb = (const float*)d_in[2];
    const float* teb   = (const float*)d_in[3];
    const float* Wp    = (const float*)d_in[4];
    const float* bp    = (const float*)d_in[5];
    const float* tadj  = (const float*)d_in[6];
    const float* adj   = (const float*)d_in[7];
    const float* wspa  = (const float*)d_in[8];
    const float* bspa  = (const float*)d_in[9];

    float* out    = (float*)d_out;
    float* outc   = out  + (size_t)BT_*N_*64;      // c:   [BT,HS,N]
    float* outdyn = outc + (size_t)BT_*HS_*N_;     // dyn: [B,HT,TT]

    char* ws = (char*)d_ws;
    unsigned int* Ppk  = (unsigned int*)ws;                          // 25.2 MB
    float* dadj  = (float*)(ws + 25165824);                          // 12.6 MB
    float* tpA   = dadj  + (size_t)BT_*HS_*N_;                       // 6.3 MB
    float* tpB   = tpA   + (size_t)BT_*8*HS_*64;                     // 6.3 MB
    float* spart = tpB   + (size_t)BT_*8*HS_*64;                     // 0.39 MB
    float* v1buf = spart + (size_t)BT_*8*64;
    float* vs0   = v1buf + (size_t)BT_*HS_*64;
    float* vs1   = vs0   + (size_t)BT_*HS_*64;
    float* sbuf  = vs1   + (size_t)BT_*HS_*64;
    float* temb  = sbuf  + (size_t)BT_*HS_*64;
    float* v2    = temb  + (size_t)B_*HT_*64;
    unsigned int* recpk = (unsigned int*)(v2 + (size_t)BT_*HS_*64);  // 25.2 MB
    float* scb = (float*)(recpk + (size_t)N_*BT_*32);                // 786 KB
    unsigned int* wpkg = (unsigned int*)dadj;                        // 8 MB (aliases dadj)
    float* bspg = (float*)(wpkg + (size_t)N_*2048);                  // 256 KB

    k_dadj<<<dim3(BT_, 16), 256, 0, stream>>>(teb, adj, dadj);
    k_PA0<<<dim3(BT_, 8), 256, 0, stream>>>(x, Wp, bp, Ppk, scb, dadj,
            tpA, spart);

    kA<1><<<dim3(BT_, 8), 256, 0, stream>>>(Ppk, scb, dadj, tpA,
            spart, v1buf, nullptr, vs0, tpB, nullptr);
    kA<2><<<dim3(BT_, 8), 256, 0, stream>>>(Ppk, scb, dadj, tpB,
            nullptr, v1buf, vs0, vs1, tpA, nullptr);
    kA<3><<<dim3(BT_, 8), 256, 0, stream>>>(Ppk, scb, dadj, tpA,
            nullptr, v1buf, vs1, nullptr, tpB, outc);
    k_s<<<dim3(BT_), 256, 0, stream>>>(tpB, sbuf);

    k_wsp<<<dim3(8, 32), 256, 0, stream>>>(ne, wspa, bspa, wpkg, bspg);

    k_dyntem<<<dim3(B_, HT_), 256, 0, stream>>>(timeb, tadj, sbuf, outdyn, temb);
    k_retv2<<<dim3(B_, 48), 256, 0, stream>>>(outdyn, temb, sbuf, v2);
    k_rec<<<dim3(BT_, 8), 256, 0, stream>>>(outc, v2, recpk);
    k_final<<<dim3(N_, 2), 256, 0, stream>>>(x, wpkg, bspg, recpk, out);
}

// Round 23
// 163.275 us; speedup vs baseline: 1.0753x; 1.0753x over previous
//
#include <hip/hip_runtime.h>
#include <math.h>

#define B_ 16
#define T_ 12
#define N_ 1024
#define D_ 64
#define HS_ 16
#define HT_ 64
#define TT_ 192
#define BT_ 192

typedef _Float16 f16x2 __attribute__((ext_vector_type(2)));
typedef _Float16 f16x8v __attribute__((ext_vector_type(8)));
typedef float f32x4v __attribute__((ext_vector_type(4)));
typedef unsigned int u32x4v __attribute__((ext_vector_type(4)));

__device__ __forceinline__ unsigned int pkrtz(float a, float b){
    auto r = __builtin_amdgcn_cvt_pkrtz(a, b);
    return __builtin_bit_cast(unsigned int, r);
}
__device__ __forceinline__ float fdot2u(unsigned int a, unsigned int b, float c){
    return __builtin_amdgcn_fdot2(__builtin_bit_cast(f16x2, a),
                                  __builtin_bit_cast(f16x2, b), c, false);
}
__device__ __forceinline__ float loF(unsigned int a){ f16x2 h = __builtin_bit_cast(f16x2, a); return (float)h.x; }
__device__ __forceinline__ float hiF(unsigned int a){ f16x2 h = __builtin_bit_cast(f16x2, a); return (float)h.y; }
__device__ __forceinline__ f32x4v mfma16(u32x4v a, u32x4v b, f32x4v c){
    return __builtin_amdgcn_mfma_f32_16x16x32_f16(
        __builtin_bit_cast(f16x8v, a), __builtin_bit_cast(f16x8v, b), c, 0, 0, 0);
}

__device__ __forceinline__ float lrelu_(float v){ return v > 0.f ? v : 0.01f*v; }
__device__ __forceinline__ float squash_sc(float sn){ return (sn/(1.f+sn))/(sqrtf(sn)+1e-8f); }

__device__ __forceinline__ float wredsum64(float v){
    #pragma unroll
    for (int mk = 1; mk < 64; mk <<= 1) v += __shfl_xor(v, mk, 64);
    return v;
}

// PLT XOR-swizzle (round-19 verified): word (d,np) at d*68 + (np ^ ((d>>3)<<2)).

// ---------------------------------------------------------------------------
// k_PA0: fused k_P (MFMA y=x@W^T+b) + kA<0>.  grid (192,8) x 256
// (round-19 best-measured configuration: inline dadj, swizzled PLT)
// ---------------------------------------------------------------------------
__global__ __launch_bounds__(256, 1) void k_PA0(const float* __restrict__ x,
        const float* __restrict__ Wp, const float* __restrict__ bp,
        unsigned int* __restrict__ Ppk, float* __restrict__ scb,
        const float* __restrict__ teb, const float* __restrict__ adj,
        float* __restrict__ dadjb,
        float* __restrict__ tpOut, float* __restrict__ spOut){
    __shared__ unsigned int xst[128*36];       // x-stage, then packed y (=PL)
    __shared__ unsigned int PLT[64*68];
    __shared__ float bL[16*130];
    __shared__ unsigned int cpk[16*68];
    __shared__ float scL[128];
    __shared__ unsigned int scpk[64];
    __shared__ float snH[2][128];
    int t = threadIdx.x, w = t >> 6, l = t & 63;
    int lr = l & 15, lk = l >> 4;
    int bt = blockIdx.x, ch = blockIdx.y;
    int n0 = ch*128;
    size_t rbase = (size_t)bt*1024 + n0;
    const float* xb = x + rbase*64;

    // ---- phase 1: stage x (f16 pairs)
    #pragma unroll
    for (int j = 0; j < 16; ++j){
        int idx = j*256 + t;
        int row = idx >> 5, cp = idx & 31;
        float2 xv = *(const float2*)(xb + row*64 + 2*cp);
        xst[row*36 + cp] = pkrtz(xv.x, xv.y);
    }
    f16x8v bf[4][2];
    float bpv[4];
    #pragma unroll
    for (int nt = 0; nt < 4; ++nt){
        #pragma unroll
        for (int ks = 0; ks < 2; ++ks){
            const float* wr = Wp + (nt*16 + lr)*64 + ks*32 + lk*8;
            u32x4v bw;
            #pragma unroll
            for (int j = 0; j < 4; ++j){
                float2 w2 = *(const float2*)(wr + 2*j);
                bw[j] = pkrtz(w2.x, w2.y);
            }
            bf[nt][ks] = __builtin_bit_cast(f16x8v, bw);
        }
        bpv[nt] = bp[nt*16 + lr];
    }
    __syncthreads();

    // ---- phase 2: y = x@W^T + b via MFMA; pack back into xst rows
    #pragma unroll
    for (int mi = 0; mi < 2; ++mi){
        int mt = 2*w + mi;
        f32x4v acc0 = {0.f,0.f,0.f,0.f}, acc1 = {0.f,0.f,0.f,0.f};
        f32x4v acc2 = {0.f,0.f,0.f,0.f}, acc3 = {0.f,0.f,0.f,0.f};
        #pragma unroll
        for (int ks = 0; ks < 2; ++ks){
            u32x4v au = *(u32x4v*)&xst[(mt*16 + lr)*36 + ks*16 + lk*4];
            f16x8v af = __builtin_bit_cast(f16x8v, au);
            acc0 = __builtin_amdgcn_mfma_f32_16x16x32_f16(af, bf[0][ks], acc0, 0, 0, 0);
            acc1 = __builtin_amdgcn_mfma_f32_16x16x32_f16(af, bf[1][ks], acc1, 0, 0, 0);
            acc2 = __builtin_amdgcn_mfma_f32_16x16x32_f16(af, bf[2][ks], acc2, 0, 0, 0);
            acc3 = __builtin_amdgcn_mfma_f32_16x16x32_f16(af, bf[3][ks], acc3, 0, 0, 0);
        }
        #pragma unroll
        for (int i = 0; i < 4; ++i){
            int row = mt*16 + lk*4 + i;
            float y0 = acc0[i] + bpv[0];
            float y1 = acc1[i] + bpv[1];
            float y2 = acc2[i] + bpv[2];
            float y3 = acc3[i] + bpv[3];
            float p0 = __shfl_xor(y0, 1, 64);
            float p1 = __shfl_xor(y1, 1, 64);
            float p2 = __shfl_xor(y2, 1, 64);
            float p3 = __shfl_xor(y3, 1, 64);
            if (!(l & 1)){
                int cb = lr >> 1;
                xst[row*36 +      cb] = pkrtz(y0, p0);
                xst[row*36 +  8 + cb] = pkrtz(y1, p1);
                xst[row*36 + 16 + cb] = pkrtz(y2, p2);
                xst[row*36 + 24 + cb] = pkrtz(y3, p3);
            }
        }
    }
    __syncthreads();

    // ---- phase 3: write Ppk + build PLT (swizzled transpose write)
    unsigned int* pb = Ppk + rbase*32;
    #pragma unroll
    for (int k = 0; k < 4; ++k){
        int idx4 = k*256 + t;
        int nn = idx4 >> 3, jq = idx4 & 7;
        uint4 u;
        u.x = xst[nn*36 + 4*jq];     u.y = xst[nn*36 + 4*jq + 1];
        u.z = xst[nn*36 + 4*jq + 2]; u.w = xst[nn*36 + 4*jq + 3];
        ((uint4*)pb)[idx4] = u;
        unsigned int px = __shfl_xor(u.x, 8, 64);
        unsigned int py = __shfl_xor(u.y, 8, 64);
        unsigned int pz = __shfl_xor(u.z, 8, 64);
        unsigned int pw = __shfl_xor(u.w, 8, 64);
        if (!(nn & 1)){
            int np = nn >> 1, d0 = jq*8;
            int cs = np ^ (jq << 2);          // swizzled column ((d>>3)=jq)
            PLT[(d0+0)*68 + cs] = (u.x & 0xFFFFu) | (px << 16);
            PLT[(d0+1)*68 + cs] = (u.x >> 16)     | (px & 0xFFFF0000u);
            PLT[(d0+2)*68 + cs] = (u.y & 0xFFFFu) | (py << 16);
            PLT[(d0+3)*68 + cs] = (u.y >> 16)     | (py & 0xFFFF0000u);
            PLT[(d0+4)*68 + cs] = (u.z & 0xFFFFu) | (pz << 16);
            PLT[(d0+5)*68 + cs] = (u.z >> 16)     | (pz & 0xFFFF0000u);
            PLT[(d0+6)*68 + cs] = (u.w & 0xFFFFu) | (pw << 16);
            PLT[(d0+7)*68 + cs] = (u.w >> 16)     | (pw & 0xFFFF0000u);
        }
    }

    // ---- phase 4: |y|^2 partials + dadj logits
    {
        int nn = t & 127, hg = t >> 7;
        float s2 = 0.f;
        #pragma unroll
        for (int j = 0; j < 4; ++j){
            uint4 pq = *(uint4*)&xst[nn*36 + hg*16 + 4*j];
            s2 += loF(pq.x)*loF(pq.x) + hiF(pq.x)*hiF(pq.x);
            s2 += loF(pq.y)*loF(pq.y) + hiF(pq.y)*hiF(pq.y);
            s2 += loF(pq.z)*loF(pq.z) + hiF(pq.z)*hiF(pq.z);
            s2 += loF(pq.w)*loF(pq.w) + hiF(pq.w)*hiF(pq.w);
        }
        snH[hg][nn] = s2;
        float tl[16];
        #pragma unroll
        for (int e = 0; e < 16; ++e) tl[e] = teb[bt*16 + e];
        #pragma unroll
        for (int i = 0; i < 8; ++i){
            int h = hg*8 + i;
            float s = 0.f;
            #pragma unroll
            for (int e = 0; e < 16; ++e)
                s += tl[e]*adj[(((e << 4) + h) << 10) + n0 + nn];
            bL[h*130 + nn] = s;
            dadjb[((size_t)bt*16 + h)*1024 + n0 + nn] = s;
        }
    }
    __syncthreads();

    // ---- phase 5: softmax + sc; pack cpk = c*sc (pairs along n)
    if (t < 128){
        int nn = t;
        float scn = squash_sc(snH[0][nn] + snH[1][nn]);
        scL[nn] = scn;
        scb[(size_t)bt*1024 + n0 + nn] = scn;
        float so = __shfl_xor(scn, 1, 64);
        if (!(nn & 1)) scpk[nn >> 1] = pkrtz(scn, so);
        float M = -1e30f;
        #pragma unroll
        for (int h = 0; h < 16; ++h) M = fmaxf(M, bL[h*130 + nn]);
        float S = 0.f; float ev[16];
        #pragma unroll
        for (int h = 0; h < 16; ++h){ ev[h] = __expf(bL[h*130 + nn] - M); S += ev[h]; }
        float inv = 1.f/S;
        #pragma unroll
        for (int h = 0; h < 16; ++h){
            float cs = ev[h]*inv*scn;
            float co = __shfl_xor(cs, 1, 64);
            if (!(nn & 1)) cpk[h*68 + (nn >> 1)] = pkrtz(cs, co);
        }
    }
    __syncthreads();

    // ---- phase 6: cP MFMA (D[h][d] = cpk x PLT) + sumP (swizzled reads)
    {
        int swd = ((w*16 + lr) >> 3) << 2;
        f32x4v acc = {0.f,0.f,0.f,0.f};
        #pragma unroll
        for (int ks = 0; ks < 4; ++ks){
            u32x4v au = *(u32x4v*)&cpk[lr*68 + ks*16 + lk*4];
            u32x4v bu = *(u32x4v*)&PLT[(w*16 + lr)*68 + ((ks*16 + lk*4) ^ swd)];
            acc = mfma16(au, bu, acc);
        }
        #pragma unroll
        for (int i = 0; i < 4; ++i){
            int h = lk*4 + i;
            tpOut[(((size_t)bt*8 + ch)*16 + h)*64 + w*16 + lr] = acc[i];
        }
    }
    if (w == 0){
        int sl = (l >> 3) << 2;
        float sp2 = 0.f;
        #pragma unroll
        for (int np4 = 0; np4 < 16; ++np4){
            uint4 pq = *(uint4*)&PLT[l*68 + ((4*np4) ^ sl)];
            uint4 sq = *(uint4*)&scpk[4*np4];
            sp2 = fdot2u(pq.x, sq.x, sp2);
            sp2 = fdot2u(pq.y, sq.y, sp2);
            sp2 = fdot2u(pq.z, sq.z, sp2);
            sp2 = fdot2u(pq.w, sq.w, sp2);
        }
        spOut[((size_t)bt*8 + ch)*64 + l] = sp2;
    }
}

// ---------------------------------------------------------------------------
// kA (modes 1-3, MFMA, swizzled PLT, PL staged).  grid (192,8) x 256
// ---------------------------------------------------------------------------
template<int MODE>
__global__ __launch_bounds__(256, 2) void kA(const unsigned int* __restrict__ Ppk,
        float* __restrict__ scb,
        float* __restrict__ dadjb,
        const float* __restrict__ tpIn, const float* __restrict__ spart,
        float* __restrict__ v1buf, const float* __restrict__ vsumIn,
        float* __restrict__ vsumOut,
        float* __restrict__ tpOut, float* __restrict__ cout){
    __shared__ unsigned int PL[128*36];
    __shared__ unsigned int PLT[64*68];
    __shared__ unsigned int vLp[16*36];
    __shared__ float bL[16*130];
    __shared__ unsigned int cpk[16*68];
    __shared__ float scL[128];
    int bt = blockIdx.x, ch = blockIdx.y;
    int t = threadIdx.x, w = t >> 6, l = t & 63;
    int lr = l & 15, lk = l >> 4;
    int n0 = ch*128;

    const uint4* Pg = (const uint4*)(Ppk + ((size_t)bt*1024 + n0)*32);
    #pragma unroll
    for (int k = 0; k < 4; ++k){
        int idx4 = t + 256*k;
        uint4 u = Pg[idx4];
        int nn = idx4 >> 3, jq = idx4 & 7;
        *(uint4*)&PL[nn*36 + 4*jq] = u;
        unsigned int px = __shfl_xor(u.x, 8, 64);
        unsigned int py = __shfl_xor(u.y, 8, 64);
        unsigned int pz = __shfl_xor(u.z, 8, 64);
        unsigned int pw = __shfl_xor(u.w, 8, 64);
        if (!(nn & 1)){
            int np = nn >> 1, d0 = jq*8;
            int cs = np ^ (jq << 2);
            PLT[(d0+0)*68 + cs] = (u.x & 0xFFFFu) | (px << 16);
            PLT[(d0+1)*68 + cs] = (u.x >> 16)     | (px & 0xFFFF0000u);
            PLT[(d0+2)*68 + cs] = (u.y & 0xFFFFu) | (py << 16);
            PLT[(d0+3)*68 + cs] = (u.y >> 16)     | (py & 0xFFFF0000u);
            PLT[(d0+4)*68 + cs] = (u.z & 0xFFFFu) | (pz << 16);
            PLT[(d0+5)*68 + cs] = (u.z >> 16)     | (pz & 0xFFFF0000u);
            PLT[(d0+6)*68 + cs] = (u.w & 0xFFFFu) | (pw << 16);
            PLT[(d0+7)*68 + cs] = (u.w >> 16)     | (pw & 0xFFFF0000u);
        }
    }
    if (t < 128) scL[t] = scb[(size_t)bt*1024 + n0 + t];
    {
        float sp = 0.f;
        if (MODE == 1){
            #pragma unroll
            for (int c = 0; c < 8; ++c) sp += spart[((size_t)bt*8 + c)*64 + l];
            sp *= (1.f/16.f);
        }
        #pragma unroll
        for (int i = 0; i < 4; ++i){
            int h = 4*w + i;
            float s = 0.f;
            #pragma unroll
            for (int c = 0; c < 8; ++c)
                s += tpIn[(((size_t)bt*8 + c)*16 + h)*64 + l];
            size_t oi = ((size_t)bt*16 + h)*64 + l;
            float vs;
            if (MODE == 1){
                float sn = wredsum64(s*s);
                float v1 = s*squash_sc(sn);
                v1buf[oi] = v1;
                float q = v1*sp;
                float sn2 = wredsum64(q*q);
                vs = q*squash_sc(sn2);
            } else {
                float q = v1buf[oi]*s;
                float sn = wredsum64(q*q);
                vs = vsumIn[oi] + q*squash_sc(sn);
            }
            if (MODE != 3) vsumOut[oi] = vs;
            float vo = __shfl_xor(vs, 1, 64);
            if (!(l & 1)) vLp[h*36 + (l >> 1)] = pkrtz(vs, vo);
        }
    }
    __syncthreads();

    // logit MFMA: wave w -> n-tiles 2w, 2w+1; D[n][h]
    #pragma unroll
    for (int mi = 0; mi < 2; ++mi){
        int mt = 2*w + mi;
        f32x4v acc = {0.f,0.f,0.f,0.f};
        #pragma unroll
        for (int ks = 0; ks < 2; ++ks){
            u32x4v au = *(u32x4v*)&PL[(mt*16 + lr)*36 + ks*16 + lk*4];
            u32x4v bu = *(u32x4v*)&vLp[lr*36 + ks*16 + lk*4];
            acc = mfma16(au, bu, acc);
        }
        #pragma unroll
        for (int i = 0; i < 4; ++i){
            int nn = mt*16 + lk*4 + i;
            float lg = acc[i] * scL[nn];
            if (MODE == 3)
                lg += dadjb[((size_t)bt*16 + lr)*1024 + n0 + nn];
            bL[lr*130 + nn] = lg;
        }
    }
    __syncthreads();

    // softmax over h per n; pack cpk = c*sc
    if (t < 128){
        int nn = t;
        float scn = scL[nn];
        float M = -1e30f;
        #pragma unroll
        for (int h = 0; h < 16; ++h) M = fmaxf(M, bL[h*130 + nn]);
        float S = 0.f; float ev[16];
        #pragma unroll
        for (int h = 0; h < 16; ++h){ ev[h] = __expf(bL[h*130 + nn] - M); S += ev[h]; }
        float inv = 1.f/S;
        #pragma unroll
        for (int h = 0; h < 16; ++h){
            float cv = ev[h]*inv;
            if (MODE == 3) cout[((size_t)bt*16 + h)*1024 + n0 + nn] = cv;
            float cs = cv*scn;
            float co = __shfl_xor(cs, 1, 64);
            if (!(nn & 1)) cpk[h*68 + (nn >> 1)] = pkrtz(cs, co);
        }
    }
    __syncthreads();

    // cP MFMA: wave w -> d-tile w; D[h][d] (swizzled B-read)
    {
        int swd = ((w*16 + lr) >> 3) << 2;
        f32x4v acc = {0.f,0.f,0.f,0.f};
        #pragma unroll
        for (int ks = 0; ks < 4; ++ks){
            u32x4v au = *(u32x4v*)&cpk[lr*68 + ks*16 + lk*4];
            u32x4v bu = *(u32x4v*)&PLT[(w*16 + lr)*68 + ((ks*16 + lk*4) ^ swd)];
            acc = mfma16(au, bu, acc);
        }
        #pragma unroll
        for (int i = 0; i < 4; ++i){
            int h = lk*4 + i;
            tpOut[(((size_t)bt*8 + ch)*16 + h)*64 + w*16 + lr] = acc[i];
        }
    }
}

// k_s: s = reduce tpart (raw)   grid 192 x 256
__global__ __launch_bounds__(256) void k_s(const float* __restrict__ tpart,
        float* __restrict__ sout){
    int bt = blockIdx.x;
    int w = threadIdx.x >> 6, l = threadIdx.x & 63;
    #pragma unroll
    for (int i = 0; i < 4; ++i){
        int h = 4*w + i;
        float s = 0.f;
        #pragma unroll
        for (int c = 0; c < 8; ++c)
            s += tpart[(((size_t)bt*8 + c)*16 + h)*64 + l];
        sout[((size_t)bt*16 + h)*64 + l] = s;
    }
}

// k_wsp: precompute w_sp/b_sp per node.  grid (8,32) x 256
__global__ __launch_bounds__(256) void k_wsp(const float* __restrict__ ne,
        const float* __restrict__ wspa, const float* __restrict__ bspa,
        unsigned int* __restrict__ wpkg, float* __restrict__ bspg){
    __shared__ float wspaL[16*512];
    __shared__ float neL[32*16];
    int ioc = blockIdx.x, nc = blockIdx.y;
    int t = threadIdx.x, w = t >> 6, o = t & 63;
    #pragma unroll
    for (int k = 0; k < 8; ++k){
        int idx4 = t + 256*k;
        int e = idx4 >> 7, j4 = idx4 & 127;
        *(float4*)&wspaL[e*512 + 4*j4] =
            *(const float4*)(wspa + (size_t)e*4096 + ioc*512 + 4*j4);
    }
    #pragma unroll
    for (int k = 0; k < 2; ++k)
        neL[k*256 + t] = ne[(size_t)nc*512 + k*256 + t];
    __syncthreads();
    int c0 = (2*w)*64 + o, c1 = (2*w+1)*64 + o;
    #pragma unroll 2
    for (int n = 0; n < 32; ++n){
        float a0 = 0.f, a1 = 0.f;
        #pragma unroll
        for (int e = 0; e < 16; ++e){
            float nv = neL[n*16 + e];
            a0 += nv*wspaL[e*512 + c0];
            a1 += nv*wspaL[e*512 + c1];
        }
        wpkg[((size_t)(nc*32 + n))*2048 + (ioc*4 + w)*64 + o] = pkrtz(a0, a1);
    }
    if (ioc == 0){
        #pragma unroll
        for (int k = 0; k < 8; ++k){
            int idx = k*256 + t;
            int n = idx >> 6, o2 = idx & 63;
            float a = 0.f;
            #pragma unroll
            for (int e = 0; e < 16; ++e)
                a += neL[n*16 + e]*bspa[e*64 + o2];
            bspg[(size_t)(nc*32 + n)*64 + o2] = a;
        }
    }
}

// k_dyntem: fused dyn + tem.  grid (16,64) x 256
__global__ __launch_bounds__(256) void k_dyntem(const float* __restrict__ timeb,
        const float* __restrict__ tadj, const float* __restrict__ sbuf,
        float* __restrict__ dyn, float* __restrict__ tem){
    __shared__ float dynL[192];
    __shared__ float part[4][64];
    int b = blockIdx.x, h = blockIdx.y, t = threadIdx.x;
    if (t < 192){
        float a = 0.f;
        #pragma unroll
        for (int e = 0; e < 16; ++e)
            a += timeb[b*16 + e]*tadj[((size_t)e*HT_ + h)*TT_ + t];
        dynL[t] = a;
        dyn[((size_t)b*HT_ + h)*TT_ + t] = a;
    }
    __syncthreads();
    int p = t >> 6, d = t & 63;
    const float* sb = sbuf + (size_t)b*TT_*64;
    float a = 0.f;
    #pragma unroll 4
    for (int k = 48*p; k < 48*p + 48; ++k)
        a += dynL[k]*(sb[(size_t)k*64 + d] + (float)((k >> 4) + 1)*(1.f/12.f));
    part[p][d] = a;
    __syncthreads();
    if (t < 64)
        tem[((size_t)b*HT_ + h)*64 + t] =
            lrelu_(part[0][t] + part[1][t] + part[2][t] + part[3][t]);
}

// ret=lrelu(sum_h dyn*tem)+s; v2=squash(ret)   grid (16,48) x 256
__global__ __launch_bounds__(256) void k_retv2(const float* __restrict__ dyn,
        const float* __restrict__ temb, const float* __restrict__ sbuf,
        float* __restrict__ v2){
    int b = blockIdx.x, kg = blockIdx.y;
    int w = threadIdx.x >> 6, l = threadIdx.x & 63;
    int k = kg*4 + w;
    const float* tb = temb + (size_t)b*HT_*64;
    float a0 = 0.f, a1 = 0.f;
    #pragma unroll 4
    for (int h = 0; h < HT_; h += 2){
        a0 += dyn[((size_t)b*HT_ + h  )*TT_ + k] * tb[(size_t)h*64 + l];
        a1 += dyn[((size_t)b*HT_ + h+1)*TT_ + k] * tb[(size_t)(h+1)*64 + l];
    }
    float a = lrelu_(a0 + a1);
    float r = a + sbuf[((size_t)b*TT_ + k)*64 + l];
    float sn = wredsum64(r*r);
    v2[((size_t)b*TT_ + k)*64 + l] = r*squash_sc(sn);
}

// recon f16 pairs, layout [n][bt][32]   grid (192,8) x 256
__global__ __launch_bounds__(256) void k_rec(const float* __restrict__ cbuf,
        const float* __restrict__ v2, unsigned int* __restrict__ recpk){
    __shared__ float vL[16*68];
    __shared__ float cL[16*132];
    int bt = blockIdx.x, nc = blockIdx.y;
    int t = threadIdx.x, l = t & 63, g = t >> 6;
    #pragma unroll
    for (int i = 0; i < 4; ++i){
        int idx = i*256 + t;
        vL[(idx>>6)*68 + (idx&63)] = v2[(size_t)bt*1024 + idx];
    }
    #pragma unroll
    for (int i = 0; i < 8; ++i){
        int idx = i*256 + t;
        cL[(idx>>7)*132 + (idx&127)] =
            cbuf[((size_t)bt*16 + (idx>>7))*1024 + nc*128 + (idx&127)];
    }
    __syncthreads();
    float vreg[16];
    #pragma unroll
    for (int h = 0; h < 16; ++h) vreg[h] = vL[h*68 + l];
    #pragma unroll 4
    for (int i = 0; i < 32; ++i){
        int nl = g + 4*i;
        float a = 0.f;
        #pragma unroll
        for (int h = 0; h < 16; ++h) a += cL[h*132 + nl]*vreg[h];
        float ap = __shfl_xor(a, 1, 64);
        if (!(l & 1))
            recpk[((size_t)(nc*128 + nl)*192 + bt)*32 + (l>>1)] = pkrtz(a, ap);
    }
}

// out = lrelu(rec @ wsp[n] + bsp[n] + x)   grid (1024,2) x 256
__global__ __launch_bounds__(256) void k_final(const float* __restrict__ x,
        const unsigned int* __restrict__ wpkg, const float* __restrict__ bspg,
        const unsigned int* __restrict__ recpk, float* __restrict__ out){
    __shared__ __align__(16) unsigned int recL[96*32];
    int n = blockIdx.x, half = blockIdx.y;
    int t = threadIdx.x, l = t & 63, g = t >> 6;
    unsigned int wr[32];
    const unsigned int* wn = wpkg + (size_t)n*2048;
    #pragma unroll
    for (int ip = 0; ip < 32; ++ip) wr[ip] = wn[ip*64 + l];
    float bsp = bspg[(size_t)n*64 + l];
    {
        const uint4* src = (const uint4*)(recpk + ((size_t)n*192 + half*96)*32);
        #pragma unroll
        for (int k = 0; k < 3; ++k)
            ((uint4*)recL)[t + 256*k] = src[t + 256*k];
    }
    __syncthreads();
    #pragma unroll 2
    for (int i = 0; i < 24; ++i){
        int r = i*4 + g;
        int bt = half*96 + r;
        const uint4* rp = (const uint4*)&recL[r*32];
        float o0 = bsp, o1 = 0.f;
        #pragma unroll
        for (int jj = 0; jj < 8; ++jj){
            uint4 rq = rp[jj];
            o0 = fdot2u(rq.x, wr[4*jj+0], o0);
            o1 = fdot2u(rq.y, wr[4*jj+1], o1);
            o0 = fdot2u(rq.z, wr[4*jj+2], o0);
            o1 = fdot2u(rq.w, wr[4*jj+3], o1);
        }
        size_t oidx = ((size_t)bt*1024 + n)*64 + l;
        out[oidx] = lrelu_(o0 + o1 + x[oidx]);
    }
}

extern "C" void kernel_launch(void* const* d_in, const int* in_sizes, int n_in,
                              void* d_out, int out_size, void* d_ws, size_t ws_size,
                              hipStream_t stream) {
    const float* x     = (const float*)d_in[0];
    const float* ne    = (const float*)d_in[1];
    const float* timeb = (const float*)d_in[2];
    const float* teb   = (const float*)d_in[3];
    const float* Wp    = (const float*)d_in[4];
    const float* bp    = (const float*)d_in[5];
    const float* tadj  = (const float*)d_in[6];
    const float* adj   = (const float*)d_in[7];
    const float* wspa  = (const float*)d_in[8];
    const float* bspa  = (const float*)d_in[9];

    float* out    = (float*)d_out;
    float* outc   = out  + (size_t)BT_*N_*64;      // c:   [BT,HS,N]
    float* outdyn = outc + (size_t)BT_*HS_*N_;     // dyn: [B,HT,TT]

    char* ws = (char*)d_ws;
    unsigned int* Ppk  = (unsigned int*)ws;                          // 25.2 MB
    float* dadj  = (float*)(ws + 25165824);                          // 12.6 MB
    float* tpA   = dadj  + (size_t)BT_*HS_*N_;                       // 6.3 MB
    float* tpB   = tpA   + (size_t)BT_*8*HS_*64;                     // 6.3 MB
    float* spart = tpB   + (size_t)BT_*8*HS_*64;                     // 0.39 MB
    float* v1buf = spart + (size_t)BT_*8*64;
    float* vs0   = v1buf + (size_t)BT_*HS_*64;
    float* vs1   = vs0   + (size_t)BT_*HS_*64;
    float* sbuf  = vs1   + (size_t)BT_*HS_*64;
    float* temb  = sbuf  + (size_t)BT_*HS_*64;
    float* v2    = temb  + (size_t)B_*HT_*64;
    unsigned int* recpk = (unsigned int*)(v2 + (size_t)BT_*HS_*64);  // 25.2 MB
    float* scb = (float*)(recpk + (size_t)N_*BT_*32);                // 786 KB
    unsigned int* wpkg = (unsigned int*)dadj;                        // 8 MB (aliases dadj)
    float* bspg = (float*)(wpkg + (size_t)N_*2048);                  // 256 KB

    // fused k_P + pass-0 sweep
    k_PA0<<<dim3(BT_, 8), 256, 0, stream>>>(x, Wp, bp, Ppk, scb, teb, adj,
            dadj, tpA, spart);

    kA<1><<<dim3(BT_, 8), 256, 0, stream>>>(Ppk, scb, dadj, tpA,
            spart, v1buf, nullptr, vs0, tpB, nullptr);
    kA<2><<<dim3(BT_, 8), 256, 0, stream>>>(Ppk, scb, dadj, tpB,
            nullptr, v1buf, vs0, vs1, tpA, nullptr);
    kA<3><<<dim3(BT_, 8), 256, 0, stream>>>(Ppk, scb, dadj, tpA,
            nullptr, v1buf, vs1, nullptr, tpB, outc);
    k_s<<<dim3(BT_), 256, 0, stream>>>(tpB, sbuf);

    k_wsp<<<dim3(8, 32), 256, 0, stream>>>(ne, wspa, bspa, wpkg, bspg);

    k_dyntem<<<dim3(B_, HT_), 256, 0, stream>>>(timeb, tadj, sbuf, outdyn, temb);
    k_retv2<<<dim3(B_, 48), 256, 0, stream>>>(outdyn, temb, sbuf, v2);
    k_rec<<<dim3(BT_, 8), 256, 0, stream>>>(outc, v2, recpk);
    k_final<<<dim3(N_, 2), 256, 0, stream>>>(x, wpkg, bspg, recpk, out);
}